// Round 6
// baseline (17962.404 us; speedup 1.0000x reference)
//
#include <hip/hip_runtime.h>

// 2-layer GRU scan: L=512, B=256, D=H=512, 3H=1536.
// Persistent cooperative kernel: 256 blocks (1/CU, LDS-pinned) x 512 threads.
// 8 groups x 32 blocks (g=bid&7); group owns 32 batch rows for the scan.
// R6: barrier-free dataflow (R5 structure) on PROVEN primitives (R2/R4):
//  - flags: per-wave 128B slots, __hip_atomic_store/load RELAXED AGENT (IF$
//    coherence point; no RMW convoy; poll64 = 64 parallel lanes + ballot).
//  - h-state: sc0 sc1 stores/loads (IF$), vmcnt(0) drain BEFORE flag post;
//    consumer: poll -> sc0 sc1 loads -> vmcnt(0) -> sched_barrier -> MFMA.
//  - roles: 0 = gh0+epilogue0+h0store (layer0 critical), 1 = gi0=x@Wi0
//    producer (runs AHEAD, x is input), 2 = gi1+epilogue1+h1store+y,
//    3 = gh1 producer. LDS handoffs: gi0 (role1->role0), gh1 (role3->role2)
//    with acquire/release LDS flags. No __syncthreads in the loop.

#define LSEQ 512
#define TH3 1536

// ws layout (bytes); total ~7.47 MB
#define WT_OFF   0                         // half WT[4][32][16][3][64][8] = 6291456
#define H0_OFF   6291456                   // half h0buf[8][2][32][512]    = 524288
#define H1_OFF   6815744                   // half h1buf[8][2][32][512]    = 524288
#define F0_OFF   7340032                   // flag0[8][64][128B]           = 65536
#define F1_OFF   7405568                   // flag1[8][64][128B]           = 65536

typedef _Float16 f16x8 __attribute__((ext_vector_type(8)));
typedef float f32x4 __attribute__((ext_vector_type(4)));

__device__ __forceinline__ float sig_(float v) { return 1.0f / (1.0f + __expf(-v)); }
__device__ __forceinline__ float tanh_(float v) { return 2.0f / (1.0f + __expf(-2.0f * v)) - 1.0f; }

// h-state transport: IF$ coherence point (R2-proven).
__device__ __forceinline__ f32x4 load16b(const void* p) {
  f32x4 r;
  asm volatile("global_load_dwordx4 %0, %1, off sc0 sc1" : "=v"(r) : "v"(p));
  return r;  // NOT ready until s_waitcnt vmcnt(0)
}
__device__ __forceinline__ void store2b(_Float16* p, _Float16 v) {
  asm volatile("global_store_short %0, %1, off sc0 sc1" :: "v"(p), "v"(v) : "memory");
}

// Flags: AGENT-scope atomics (execute at IF$; R2/R4-proven visibility).
__device__ __forceinline__ void astore(unsigned int* p, unsigned int v) {
  __hip_atomic_store(p, v, __ATOMIC_RELAXED, __HIP_MEMORY_SCOPE_AGENT);
}
__device__ __forceinline__ unsigned int aload(unsigned int* p) {
  return __hip_atomic_load(p, __ATOMIC_RELAXED, __HIP_MEMORY_SCOPE_AGENT);
}
// 64-lane parallel poll: lane l watches slot l; exit when ALL >= target.
__device__ __forceinline__ void poll64(char* base, int lane, unsigned int target) {
  unsigned int* p = (unsigned int*)(base + lane * 128);
  while (__ballot(aload(p) >= target) != ~0ull) {}
}
__device__ __forceinline__ void lds_post(unsigned int* f, unsigned int v) {
  __hip_atomic_store(f, v, __ATOMIC_RELEASE, __HIP_MEMORY_SCOPE_WORKGROUP);
}
__device__ __forceinline__ void lds_poll(unsigned int* f, unsigned int v) {
  while (__hip_atomic_load(f, __ATOMIC_ACQUIRE, __HIP_MEMORY_SCOPE_WORKGROUP) < v) {}
}

// Weight transpose fp32 -> fp16 MFMA B-fragment layout (unchanged).
__global__ void prep_kernel(const float* __restrict__ Wh0, const float* __restrict__ Wi1,
                            const float* __restrict__ Wh1, const float* __restrict__ Wi0,
                            char* __restrict__ ws) {
  const int b = blockIdx.x;          // 2048 blocks
  const int w = b >> 9;              // 0:Wh0 1:Wi1 2:Wh1 3:Wi0
  const int k = b & 511;
  const float* src = (w == 0) ? Wh0 : (w == 1) ? Wi1 : (w == 2) ? Wh1 : Wi0;
  _Float16* dst = (_Float16*)(ws + WT_OFF);
  const int kc = k >> 5;
  const int lthi = ((k >> 3) & 3) << 4;
  const int e = k & 7;
  for (int col = threadIdx.x; col < TH3; col += 256) {
    float v = src[(size_t)k * TH3 + col];
    int nt = col >> 9, c = col & 511, cid = c >> 4, j = c & 15;
    size_t idx = (size_t)(w * 32 + cid) * 24576 + (size_t)((kc * 3 + nt) * 64 + lthi + j) * 8 + e;
    dst[idx] = (_Float16)v;
  }
  if (b == 0) {  // zero both flag arrays every call (replay-safe, stream-ordered)
    unsigned int* z = (unsigned int*)(ws + F0_OFF);
    for (int i = threadIdx.x; i < 32768; i += 256) z[i] = 0u;
  }
}

__global__ void __launch_bounds__(512, 2)
gru_kernel(const float* __restrict__ carry, const float* __restrict__ x,
           const float* __restrict__ bh0, const float* __restrict__ bh1,
           float* __restrict__ out, char* __restrict__ ws) {
  extern __shared__ char smem[];
  _Float16* Wlds = (_Float16*)smem;        // 147456 B: Wh0,Wi1,Wh1 fragment slices
  float* gi0buf = (float*)(smem + 147456); // 6144 B: [3 nt][32 row][16 col]
  float* gh1buf = (float*)(smem + 153600); // 6144 B: [3 nt][32 row][16 col]
  __shared__ unsigned int sf[8];  // 0,1:gi0_rdy[mh] 2,3:gi0_cons 4,5:gh1_rdy 6,7:gh1_cons

  const int tid = threadIdx.x;
  const int wid = tid >> 6, lane = tid & 63;
  const int l16 = lane & 15, lhi = lane >> 4;
  const int mhalf = wid & 1, role = wid >> 1;  // 0:gh0+ep0 1:gi0 2:gi1+ep1 3:gh1
  const int g = blockIdx.x & 7, cid = blockIdx.x >> 3;

  if (tid < 8) sf[tid] = 0u;

  _Float16* wt = (_Float16*)(ws + WT_OFF);
  _Float16* h0buf = (_Float16*)(ws + H0_OFF) + (size_t)g * 32768;  // [2 parity][32 row][512]
  _Float16* h1buf = (_Float16*)(ws + H1_OFF) + (size_t)g * 32768;
  char* f0g = ws + F0_OFF + (size_t)g * 64 * 128;   // slot (cid*2+mhalf)*128
  char* f1g = ws + F1_OFF + (size_t)g * 64 * 128;
  unsigned int* myf0 = (unsigned int*)(f0g + (cid * 2 + mhalf) * 128);
  unsigned int* myf1 = (unsigned int*)(f1g + (cid * 2 + mhalf) * 128);

  // Stage recurrent-weight fragments into LDS.
  for (int w = 0; w < 3; ++w) {
    const f16x8* s8 = (const f16x8*)(wt + (size_t)(w * 32 + cid) * 24576);
    f16x8* d8 = (f16x8*)(Wlds + w * 24576);
    for (int i = tid; i < 3072; i += 512) d8[i] = s8[i];
  }
  __syncthreads();  // weights + sf ready; last block-wide sync

  const f16x8* Wb0 = (const f16x8*)Wlds;                // Wh0 (LDS)
  const f16x8* Wb1 = (const f16x8*)(Wlds + 24576);      // Wi1 (LDS)
  const f16x8* Wb2 = (const f16x8*)(Wlds + 2 * 24576);  // Wh1 (LDS)
  const f16x8* WbX = (const f16x8*)(wt + (size_t)(3 * 32 + cid) * 24576);  // Wi0 (L2)

  const int hcol = cid * 16 + l16;
  const int rowq0 = mhalf * 16 + 4 * lhi;  // C/D rows (m89-verified layout)

  if (role == 0) {  // ======== layer0 critical: gh0 + epilogue + h0 store ========
    float bR = bh0[hcol], bZ = bh0[512 + hcol], bN = bh0[1024 + hcol];
    f32x4 hst;
#pragma unroll
    for (int q = 0; q < 4; ++q) {
      float h = carry[(size_t)(g * 32 + rowq0 + q) * 1024 + hcol];
      hst[q] = h;
      store2b(&h0buf[16384 + (rowq0 + q) * 512 + hcol], (_Float16)h);  // h0[-1], parity 1
    }
    asm volatile("s_waitcnt vmcnt(0)" ::: "memory");
    if (lane == 0) astore(myf0, 1u);
    for (int t = 0; t < LSEQ; ++t) {
      poll64(f0g, lane, (unsigned)(t + 1));  // h0[t-1] ready (all blocks)
      const _Float16* Ap = h0buf + ((t + 1) & 1) * 16384 + (mhalf * 16 + l16) * 512 + 8 * lhi;
      f16x8 afr[16];
#pragma unroll
      for (int kc = 0; kc < 16; ++kc) afr[kc] = __builtin_bit_cast(f16x8, load16b(Ap + kc * 32));
      asm volatile("s_waitcnt vmcnt(0)" ::: "memory");
      __builtin_amdgcn_sched_barrier(0);
      f32x4 a0 = {0,0,0,0}, a1 = {0,0,0,0}, a2 = {0,0,0,0};
#pragma unroll
      for (int kc = 0; kc < 16; ++kc) {
        a0 = __builtin_amdgcn_mfma_f32_16x16x32_f16(afr[kc], Wb0[(kc*3+0)*64+lane], a0, 0,0,0);
        a1 = __builtin_amdgcn_mfma_f32_16x16x32_f16(afr[kc], Wb0[(kc*3+1)*64+lane], a1, 0,0,0);
        a2 = __builtin_amdgcn_mfma_f32_16x16x32_f16(afr[kc], Wb0[(kc*3+2)*64+lane], a2, 0,0,0);
      }
      lds_poll(&sf[0 + mhalf], (unsigned)(t + 1));  // gi0[t] present
      float hnew[4];
#pragma unroll
      for (int q = 0; q < 4; ++q) {
        const int row = rowq0 + q;
        float giR = gi0buf[(0*32 + row)*16 + l16];
        float giZ = gi0buf[(1*32 + row)*16 + l16];
        float giN = gi0buf[(2*32 + row)*16 + l16];
        float r = sig_(giR + a0[q] + bR);
        float z = sig_(giZ + a1[q] + bZ);
        float n = tanh_(giN + r * (a2[q] + bN));
        hnew[q] = (1.0f - z) * n + z * hst[q];
        hst[q] = hnew[q];
      }
      poll64(f1g, lane, (unsigned)t);  // WAR: all role2 stored h1[t-2] (=> read h0[t-2])
#pragma unroll
      for (int q = 0; q < 4; ++q)
        store2b(&h0buf[(t & 1) * 16384 + (rowq0 + q) * 512 + hcol], (_Float16)hnew[q]);
      asm volatile("s_waitcnt vmcnt(0)" ::: "memory");
      if (lane == 0) astore(myf0, (unsigned)(t + 2));
      if (lane == 0) lds_post(&sf[2 + mhalf], (unsigned)(t + 1));  // consumed gi0[t]
    }
#pragma unroll
    for (int q = 0; q < 4; ++q)
      out[(size_t)(g * 32 + rowq0 + q) * 1024 + hcol] = hst[q];  // carry h0
  } else if (role == 1) {  // ======== gi0 = x[t] @ Wi0 producer (runs ahead) ========
    for (int t = 0; t < LSEQ; ++t) {
      const float* xp = x + ((size_t)t * 256 + g * 32 + mhalf * 16 + l16) * 512 + 8 * lhi;
      f32x4 a0 = {0,0,0,0}, a1 = {0,0,0,0}, a2 = {0,0,0,0};
#pragma unroll
      for (int kc = 0; kc < 16; ++kc) {
        f32x4 xa = *(const f32x4*)(xp + kc * 32);
        f32x4 xb = *(const f32x4*)(xp + kc * 32 + 4);
        f16x8 a;
        a[0]=(_Float16)xa[0]; a[1]=(_Float16)xa[1]; a[2]=(_Float16)xa[2]; a[3]=(_Float16)xa[3];
        a[4]=(_Float16)xb[0]; a[5]=(_Float16)xb[1]; a[6]=(_Float16)xb[2]; a[7]=(_Float16)xb[3];
        a0 = __builtin_amdgcn_mfma_f32_16x16x32_f16(a, WbX[(kc*3+0)*64+lane], a0, 0,0,0);
        a1 = __builtin_amdgcn_mfma_f32_16x16x32_f16(a, WbX[(kc*3+1)*64+lane], a1, 0,0,0);
        a2 = __builtin_amdgcn_mfma_f32_16x16x32_f16(a, WbX[(kc*3+2)*64+lane], a2, 0,0,0);
      }
      lds_poll(&sf[2 + mhalf], (unsigned)t);  // role0 consumed gi0[t-1]
#pragma unroll
      for (int q = 0; q < 4; ++q) {
        const int row = rowq0 + q;
        gi0buf[(0*32 + row)*16 + l16] = a0[q];
        gi0buf[(1*32 + row)*16 + l16] = a1[q];
        gi0buf[(2*32 + row)*16 + l16] = a2[q];
      }
      if (lane == 0) lds_post(&sf[0 + mhalf], (unsigned)(t + 1));
    }
  } else if (role == 2) {  // ======== layer1 critical: gi1 + epilogue + h1 store + y ========
    float bR = bh1[hcol], bZ = bh1[512 + hcol], bN = bh1[1024 + hcol];
    f32x4 hst;
#pragma unroll
    for (int q = 0; q < 4; ++q) {
      float h = carry[(size_t)(g * 32 + rowq0 + q) * 1024 + 512 + hcol];
      hst[q] = h;
      store2b(&h1buf[16384 + (rowq0 + q) * 512 + hcol], (_Float16)h);  // h1[-1], parity 1
    }
    asm volatile("s_waitcnt vmcnt(0)" ::: "memory");
    if (lane == 0) astore(myf1, 1u);
    for (int t = 0; t < LSEQ; ++t) {
      poll64(f0g, lane, (unsigned)(t + 2));  // h0[t] ready (all blocks)
      const _Float16* Ap = h0buf + (t & 1) * 16384 + (mhalf * 16 + l16) * 512 + 8 * lhi;
      f16x8 afr[16];
#pragma unroll
      for (int kc = 0; kc < 16; ++kc) afr[kc] = __builtin_bit_cast(f16x8, load16b(Ap + kc * 32));
      asm volatile("s_waitcnt vmcnt(0)" ::: "memory");
      __builtin_amdgcn_sched_barrier(0);
      f32x4 a0 = {0,0,0,0}, a1 = {0,0,0,0}, a2 = {0,0,0,0};
#pragma unroll
      for (int kc = 0; kc < 16; ++kc) {
        a0 = __builtin_amdgcn_mfma_f32_16x16x32_f16(afr[kc], Wb1[(kc*3+0)*64+lane], a0, 0,0,0);
        a1 = __builtin_amdgcn_mfma_f32_16x16x32_f16(afr[kc], Wb1[(kc*3+1)*64+lane], a1, 0,0,0);
        a2 = __builtin_amdgcn_mfma_f32_16x16x32_f16(afr[kc], Wb1[(kc*3+2)*64+lane], a2, 0,0,0);
      }
      lds_poll(&sf[4 + mhalf], (unsigned)(t + 1));  // gh1[t] present
      float hnew[4];
#pragma unroll
      for (int q = 0; q < 4; ++q) {
        const int row = rowq0 + q;
        float ghR = gh1buf[(0*32 + row)*16 + l16];
        float ghZ = gh1buf[(1*32 + row)*16 + l16];
        float ghN = gh1buf[(2*32 + row)*16 + l16];
        float r = sig_(a0[q] + ghR + bR);
        float z = sig_(a1[q] + ghZ + bZ);
        float n = tanh_(a2[q] + r * (ghN + bN));
        hnew[q] = (1.0f - z) * n + z * hst[q];
        hst[q] = hnew[q];
      }
      poll64(f1g, lane, (unsigned)(t + 1));  // WAR: all role2 stored h1[t-1] (=> role3 read h1[t-2])
#pragma unroll
      for (int q = 0; q < 4; ++q)
        store2b(&h1buf[(t & 1) * 16384 + (rowq0 + q) * 512 + hcol], (_Float16)hnew[q]);
      asm volatile("s_waitcnt vmcnt(0)" ::: "memory");
      if (lane == 0) astore(myf1, (unsigned)(t + 2));
      if (lane == 0) lds_post(&sf[6 + mhalf], (unsigned)(t + 1));  // consumed gh1[t]
#pragma unroll
      for (int q = 0; q < 4; ++q)   // y[t] (plain cached stores, off critical path)
        out[(size_t)262144 + ((size_t)t * 256 + g * 32 + rowq0 + q) * 512 + hcol] = hnew[q];
    }
#pragma unroll
    for (int q = 0; q < 4; ++q)
      out[(size_t)(g * 32 + rowq0 + q) * 1024 + 512 + hcol] = hst[q];  // carry h1
  } else {  // ======== role 3: gh1 = h1[t-1] @ Wh1 producer ========
    for (int t = 0; t < LSEQ; ++t) {
      poll64(f1g, lane, (unsigned)(t + 1));  // h1[t-1] ready (all blocks)
      const _Float16* Ap = h1buf + ((t + 1) & 1) * 16384 + (mhalf * 16 + l16) * 512 + 8 * lhi;
      f16x8 afr[16];
#pragma unroll
      for (int kc = 0; kc < 16; ++kc) afr[kc] = __builtin_bit_cast(f16x8, load16b(Ap + kc * 32));
      asm volatile("s_waitcnt vmcnt(0)" ::: "memory");
      __builtin_amdgcn_sched_barrier(0);
      f32x4 a0 = {0,0,0,0}, a1 = {0,0,0,0}, a2 = {0,0,0,0};
#pragma unroll
      for (int kc = 0; kc < 16; ++kc) {
        a0 = __builtin_amdgcn_mfma_f32_16x16x32_f16(afr[kc], Wb2[(kc*3+0)*64+lane], a0, 0,0,0);
        a1 = __builtin_amdgcn_mfma_f32_16x16x32_f16(afr[kc], Wb2[(kc*3+1)*64+lane], a1, 0,0,0);
        a2 = __builtin_amdgcn_mfma_f32_16x16x32_f16(afr[kc], Wb2[(kc*3+2)*64+lane], a2, 0,0,0);
      }
      lds_poll(&sf[6 + mhalf], (unsigned)t);  // role2 consumed gh1[t-1]
#pragma unroll
      for (int q = 0; q < 4; ++q) {
        const int row = rowq0 + q;
        gh1buf[(0*32 + row)*16 + l16] = a0[q];
        gh1buf[(1*32 + row)*16 + l16] = a1[q];
        gh1buf[(2*32 + row)*16 + l16] = a2[q];
      }
      if (lane == 0) lds_post(&sf[4 + mhalf], (unsigned)(t + 1));
    }
  }
}

extern "C" void kernel_launch(void* const* d_in, const int* in_sizes, int n_in,
                              void* d_out, int out_size, void* d_ws, size_t ws_size,
                              hipStream_t stream) {
  const float* carry = (const float*)d_in[0];
  const float* x     = (const float*)d_in[1];
  const float* Wi0   = (const float*)d_in[2];
  const float* Wh0   = (const float*)d_in[3];
  const float* bh0   = (const float*)d_in[4];
  const float* Wi1   = (const float*)d_in[5];
  const float* Wh1   = (const float*)d_in[6];
  const float* bh1   = (const float*)d_in[7];
  float* out = (float*)d_out;
  char* ws = (char*)d_ws;

  prep_kernel<<<2048, 256, 0, stream>>>(Wh0, Wi1, Wh1, Wi0, ws);

  (void)hipFuncSetAttribute(reinterpret_cast<const void*>(gru_kernel),
                            hipFuncAttributeMaxDynamicSharedMemorySize, 159744);

  void* args[] = {(void*)&carry, (void*)&x, (void*)&bh0, (void*)&bh1, (void*)&out, (void*)&ws};
  (void)hipLaunchCooperativeKernel(reinterpret_cast<void*>(gru_kernel),
                                   dim3(256), dim3(512), args, 159744, stream);
}

// Round 7
// 17866.849 us; speedup vs baseline: 1.0053x; 1.0053x over previous
//
#include <hip/hip_runtime.h>

// 2-layer GRU scan: L=512, B=256, D=H=512, 3H=1536.
// Persistent cooperative kernel: 256 blocks (1/CU, LDS-pinned) x 512 threads.
// R7 = R6 (passing dataflow + atomic-IF$ flags, verbatim) + XCD-local h-state:
//  - FAST path (XCC-verified groups): h stores PLAIN (write-back -> stay dirty
//    in the shared XCD L2; CDNA L1 is write-through), h loads sc0 (bypass
//    stale L1, hit shared L2). Kills the 24.6MB/step uncached IF$ re-fetch
//    (R6: FETCH 11.5GB at ~0.7-1TB/s = the 35us/step wall).
//  - Flags stay AGENT-atomic at IF$ (R6-proven): data visibility is via the
//    shared L2, independent of flag location. Polls throttled with s_sleep.
//  - Fallback (discovery verify fails): exact R6 transport (sc0 sc1 + bid
//    groups) — passes at R6 speed, never hangs (R4-proven machinery).

#define LSEQ 512
#define TH3 1536

// ws layout (bytes); total ~7.48 MB
#define WT_OFF   0                         // half WT[4][32][16][3][64][8] = 6291456
#define H0_OFF   6291456                   // half h0buf[8][2][32][512]    = 524288
#define H1_OFF   6815744                   // half h1buf[8][2][32][512]    = 524288
#define F0_OFF   7340032                   // flag0[8][64][128B]           = 65536
#define F1_OFF   7405568                   // flag1[8][64][128B]           = 65536
#define RANK_OFF 7471104                   // uint rank[8][64]             = 2048
#define GBAR_OFF 7473152                   // uint gbar[64]                = 256
#define BAD_OFF  7473408                   // uint bad[64]                 = 256

typedef _Float16 f16x8 __attribute__((ext_vector_type(8)));
typedef float f32x4 __attribute__((ext_vector_type(4)));

__device__ __forceinline__ float sig_(float v) { return 1.0f / (1.0f + __expf(-v)); }
__device__ __forceinline__ float tanh_(float v) { return 2.0f / (1.0f + __expf(-2.0f * v)) - 1.0f; }

// h-state transport. FAST: plain store (dirty in shared XCD L2) + sc0 load
// (L1 bypass, L2 hit). SLOW: sc0 sc1 both ways (IF$, R2/R6-proven).
template <bool FAST>
__device__ __forceinline__ f32x4 load16h(const void* p) {
  f32x4 r;
  if (FAST) asm volatile("global_load_dwordx4 %0, %1, off sc0" : "=v"(r) : "v"(p));
  else      asm volatile("global_load_dwordx4 %0, %1, off sc0 sc1" : "=v"(r) : "v"(p));
  return r;  // NOT ready until s_waitcnt vmcnt(0)
}
template <bool FAST>
__device__ __forceinline__ void store2h(_Float16* p, _Float16 v) {
  if (FAST) asm volatile("global_store_short %0, %1, off" :: "v"(p), "v"(v) : "memory");
  else      asm volatile("global_store_short %0, %1, off sc0 sc1" :: "v"(p), "v"(v) : "memory");
}

// Flags: AGENT-scope atomics at IF$ (R6-proven transport).
__device__ __forceinline__ void astore(unsigned int* p, unsigned int v) {
  __hip_atomic_store(p, v, __ATOMIC_RELAXED, __HIP_MEMORY_SCOPE_AGENT);
}
__device__ __forceinline__ unsigned int aload(unsigned int* p) {
  return __hip_atomic_load(p, __ATOMIC_RELAXED, __HIP_MEMORY_SCOPE_AGENT);
}
// 64-lane parallel poll with throttle: lane l watches slot l; exit when ALL >= target.
__device__ __forceinline__ void poll64(char* base, int lane, unsigned int target) {
  unsigned int* p = (unsigned int*)(base + lane * 128);
  while (__ballot(aload(p) >= target) != ~0ull) __builtin_amdgcn_s_sleep(1);
}
__device__ __forceinline__ void lds_post(unsigned int* f, unsigned int v) {
  __hip_atomic_store(f, v, __ATOMIC_RELEASE, __HIP_MEMORY_SCOPE_WORKGROUP);
}
__device__ __forceinline__ void lds_poll(unsigned int* f, unsigned int v) {
  while (__hip_atomic_load(f, __ATOMIC_ACQUIRE, __HIP_MEMORY_SCOPE_WORKGROUP) < v) {}
}

// Weight transpose fp32 -> fp16 MFMA B-fragment layout (unchanged).
__global__ void prep_kernel(const float* __restrict__ Wh0, const float* __restrict__ Wi1,
                            const float* __restrict__ Wh1, const float* __restrict__ Wi0,
                            char* __restrict__ ws) {
  const int b = blockIdx.x;          // 2048 blocks
  const int w = b >> 9;              // 0:Wh0 1:Wi1 2:Wh1 3:Wi0
  const int k = b & 511;
  const float* src = (w == 0) ? Wh0 : (w == 1) ? Wi1 : (w == 2) ? Wh1 : Wi0;
  _Float16* dst = (_Float16*)(ws + WT_OFF);
  const int kc = k >> 5;
  const int lthi = ((k >> 3) & 3) << 4;
  const int e = k & 7;
  for (int col = threadIdx.x; col < TH3; col += 256) {
    float v = src[(size_t)k * TH3 + col];
    int nt = col >> 9, c = col & 511, cid = c >> 4, j = c & 15;
    size_t idx = (size_t)(w * 32 + cid) * 24576 + (size_t)((kc * 3 + nt) * 64 + lthi + j) * 8 + e;
    dst[idx] = (_Float16)v;
  }
  if (b == 0) {  // zero flags + discovery counters (every call, stream-ordered)
    unsigned int* z = (unsigned int*)(ws + F0_OFF);
    for (int i = threadIdx.x; i < 33408; i += 256) z[i] = 0u;
  }
}

template <bool FAST>
__device__ void run_scan(int g, int cid, const float* carry, const float* x,
                         const float* bh0, const float* bh1, float* out,
                         char* ws, _Float16* Wlds, float* gi0buf, float* gh1buf,
                         unsigned int* sf) {
  const int tid = threadIdx.x;
  const int wid = tid >> 6, lane = tid & 63;
  const int l16 = lane & 15, lhi = lane >> 4;
  const int mhalf = wid & 1, role = wid >> 1;  // 0:gh0+ep0 1:gi0 2:gi1+ep1 3:gh1

  _Float16* wt = (_Float16*)(ws + WT_OFF);
  _Float16* h0buf = (_Float16*)(ws + H0_OFF) + (size_t)g * 32768;  // [2 parity][32 row][512]
  _Float16* h1buf = (_Float16*)(ws + H1_OFF) + (size_t)g * 32768;
  char* f0g = ws + F0_OFF + (size_t)g * 64 * 128;   // slot (cid*2+mhalf)*128
  char* f1g = ws + F1_OFF + (size_t)g * 64 * 128;
  unsigned int* myf0 = (unsigned int*)(f0g + (cid * 2 + mhalf) * 128);
  unsigned int* myf1 = (unsigned int*)(f1g + (cid * 2 + mhalf) * 128);

  const f16x8* Wb0 = (const f16x8*)Wlds;                // Wh0 (LDS)
  const f16x8* Wb1 = (const f16x8*)(Wlds + 24576);      // Wi1 (LDS)
  const f16x8* Wb2 = (const f16x8*)(Wlds + 2 * 24576);  // Wh1 (LDS)
  const f16x8* WbX = (const f16x8*)(wt + (size_t)(3 * 32 + cid) * 24576);  // Wi0 (L2)

  const int hcol = cid * 16 + l16;
  const int rowq0 = mhalf * 16 + 4 * lhi;  // C/D rows (m89-verified layout)

  if (role == 0) {  // ======== layer0 critical: gh0 + epilogue + h0 store ========
    float bR = bh0[hcol], bZ = bh0[512 + hcol], bN = bh0[1024 + hcol];
    f32x4 hst;
#pragma unroll
    for (int q = 0; q < 4; ++q) {
      float h = carry[(size_t)(g * 32 + rowq0 + q) * 1024 + hcol];
      hst[q] = h;
      store2h<FAST>(&h0buf[16384 + (rowq0 + q) * 512 + hcol], (_Float16)h);  // h0[-1], parity 1
    }
    asm volatile("s_waitcnt vmcnt(0)" ::: "memory");
    if (lane == 0) astore(myf0, 1u);
    for (int t = 0; t < LSEQ; ++t) {
      poll64(f0g, lane, (unsigned)(t + 1));  // h0[t-1] ready (all blocks)
      const _Float16* Ap = h0buf + ((t + 1) & 1) * 16384 + (mhalf * 16 + l16) * 512 + 8 * lhi;
      f16x8 afr[16];
#pragma unroll
      for (int kc = 0; kc < 16; ++kc) afr[kc] = __builtin_bit_cast(f16x8, load16h<FAST>(Ap + kc * 32));
      asm volatile("s_waitcnt vmcnt(0)" ::: "memory");
      __builtin_amdgcn_sched_barrier(0);
      f32x4 a0 = {0,0,0,0}, a1 = {0,0,0,0}, a2 = {0,0,0,0};
#pragma unroll
      for (int kc = 0; kc < 16; ++kc) {
        a0 = __builtin_amdgcn_mfma_f32_16x16x32_f16(afr[kc], Wb0[(kc*3+0)*64+lane], a0, 0,0,0);
        a1 = __builtin_amdgcn_mfma_f32_16x16x32_f16(afr[kc], Wb0[(kc*3+1)*64+lane], a1, 0,0,0);
        a2 = __builtin_amdgcn_mfma_f32_16x16x32_f16(afr[kc], Wb0[(kc*3+2)*64+lane], a2, 0,0,0);
      }
      lds_poll(&sf[0 + mhalf], (unsigned)(t + 1));  // gi0[t] present
      float hnew[4];
#pragma unroll
      for (int q = 0; q < 4; ++q) {
        const int row = rowq0 + q;
        float giR = gi0buf[(0*32 + row)*16 + l16];
        float giZ = gi0buf[(1*32 + row)*16 + l16];
        float giN = gi0buf[(2*32 + row)*16 + l16];
        float r = sig_(giR + a0[q] + bR);
        float z = sig_(giZ + a1[q] + bZ);
        float n = tanh_(giN + r * (a2[q] + bN));
        hnew[q] = (1.0f - z) * n + z * hst[q];
        hst[q] = hnew[q];
      }
      poll64(f1g, lane, (unsigned)t);  // WAR: all role2 stored h1[t-2] (=> read h0[t-2])
#pragma unroll
      for (int q = 0; q < 4; ++q)
        store2h<FAST>(&h0buf[(t & 1) * 16384 + (rowq0 + q) * 512 + hcol], (_Float16)hnew[q]);
      asm volatile("s_waitcnt vmcnt(0)" ::: "memory");
      if (lane == 0) astore(myf0, (unsigned)(t + 2));
      if (lane == 0) lds_post(&sf[2 + mhalf], (unsigned)(t + 1));  // consumed gi0[t]
    }
#pragma unroll
    for (int q = 0; q < 4; ++q)
      out[(size_t)(g * 32 + rowq0 + q) * 1024 + hcol] = hst[q];  // carry h0
  } else if (role == 1) {  // ======== gi0 = x[t] @ Wi0 producer (runs ahead) ========
    for (int t = 0; t < LSEQ; ++t) {
      const float* xp = x + ((size_t)t * 256 + g * 32 + mhalf * 16 + l16) * 512 + 8 * lhi;
      f32x4 a0 = {0,0,0,0}, a1 = {0,0,0,0}, a2 = {0,0,0,0};
#pragma unroll
      for (int kc = 0; kc < 16; ++kc) {
        f32x4 xa = *(const f32x4*)(xp + kc * 32);
        f32x4 xb = *(const f32x4*)(xp + kc * 32 + 4);
        f16x8 a;
        a[0]=(_Float16)xa[0]; a[1]=(_Float16)xa[1]; a[2]=(_Float16)xa[2]; a[3]=(_Float16)xa[3];
        a[4]=(_Float16)xb[0]; a[5]=(_Float16)xb[1]; a[6]=(_Float16)xb[2]; a[7]=(_Float16)xb[3];
        a0 = __builtin_amdgcn_mfma_f32_16x16x32_f16(a, WbX[(kc*3+0)*64+lane], a0, 0,0,0);
        a1 = __builtin_amdgcn_mfma_f32_16x16x32_f16(a, WbX[(kc*3+1)*64+lane], a1, 0,0,0);
        a2 = __builtin_amdgcn_mfma_f32_16x16x32_f16(a, WbX[(kc*3+2)*64+lane], a2, 0,0,0);
      }
      lds_poll(&sf[2 + mhalf], (unsigned)t);  // role0 consumed gi0[t-1]
#pragma unroll
      for (int q = 0; q < 4; ++q) {
        const int row = rowq0 + q;
        gi0buf[(0*32 + row)*16 + l16] = a0[q];
        gi0buf[(1*32 + row)*16 + l16] = a1[q];
        gi0buf[(2*32 + row)*16 + l16] = a2[q];
      }
      if (lane == 0) lds_post(&sf[0 + mhalf], (unsigned)(t + 1));
    }
  } else if (role == 2) {  // ======== layer1 critical: gi1 + epilogue + h1 store + y ========
    float bR = bh1[hcol], bZ = bh1[512 + hcol], bN = bh1[1024 + hcol];
    f32x4 hst;
#pragma unroll
    for (int q = 0; q < 4; ++q) {
      float h = carry[(size_t)(g * 32 + rowq0 + q) * 1024 + 512 + hcol];
      hst[q] = h;
      store2h<FAST>(&h1buf[16384 + (rowq0 + q) * 512 + hcol], (_Float16)h);  // h1[-1], parity 1
    }
    asm volatile("s_waitcnt vmcnt(0)" ::: "memory");
    if (lane == 0) astore(myf1, 1u);
    for (int t = 0; t < LSEQ; ++t) {
      poll64(f0g, lane, (unsigned)(t + 2));  // h0[t] ready (all blocks)
      const _Float16* Ap = h0buf + (t & 1) * 16384 + (mhalf * 16 + l16) * 512 + 8 * lhi;
      f16x8 afr[16];
#pragma unroll
      for (int kc = 0; kc < 16; ++kc) afr[kc] = __builtin_bit_cast(f16x8, load16h<FAST>(Ap + kc * 32));
      asm volatile("s_waitcnt vmcnt(0)" ::: "memory");
      __builtin_amdgcn_sched_barrier(0);
      f32x4 a0 = {0,0,0,0}, a1 = {0,0,0,0}, a2 = {0,0,0,0};
#pragma unroll
      for (int kc = 0; kc < 16; ++kc) {
        a0 = __builtin_amdgcn_mfma_f32_16x16x32_f16(afr[kc], Wb1[(kc*3+0)*64+lane], a0, 0,0,0);
        a1 = __builtin_amdgcn_mfma_f32_16x16x32_f16(afr[kc], Wb1[(kc*3+1)*64+lane], a1, 0,0,0);
        a2 = __builtin_amdgcn_mfma_f32_16x16x32_f16(afr[kc], Wb1[(kc*3+2)*64+lane], a2, 0,0,0);
      }
      lds_poll(&sf[4 + mhalf], (unsigned)(t + 1));  // gh1[t] present
      float hnew[4];
#pragma unroll
      for (int q = 0; q < 4; ++q) {
        const int row = rowq0 + q;
        float ghR = gh1buf[(0*32 + row)*16 + l16];
        float ghZ = gh1buf[(1*32 + row)*16 + l16];
        float ghN = gh1buf[(2*32 + row)*16 + l16];
        float r = sig_(a0[q] + ghR + bR);
        float z = sig_(a1[q] + ghZ + bZ);
        float n = tanh_(a2[q] + r * (ghN + bN));
        hnew[q] = (1.0f - z) * n + z * hst[q];
        hst[q] = hnew[q];
      }
      poll64(f1g, lane, (unsigned)(t + 1));  // WAR: all stored h1[t-1] (=> role3 read h1[t-2])
#pragma unroll
      for (int q = 0; q < 4; ++q)
        store2h<FAST>(&h1buf[(t & 1) * 16384 + (rowq0 + q) * 512 + hcol], (_Float16)hnew[q]);
      asm volatile("s_waitcnt vmcnt(0)" ::: "memory");
      if (lane == 0) astore(myf1, (unsigned)(t + 2));
      if (lane == 0) lds_post(&sf[6 + mhalf], (unsigned)(t + 1));  // consumed gh1[t]
#pragma unroll
      for (int q = 0; q < 4; ++q)   // y[t] (plain cached stores, off critical path)
        out[(size_t)262144 + ((size_t)t * 256 + g * 32 + rowq0 + q) * 512 + hcol] = hnew[q];
    }
#pragma unroll
    for (int q = 0; q < 4; ++q)
      out[(size_t)(g * 32 + rowq0 + q) * 1024 + 512 + hcol] = hst[q];  // carry h1
  } else {  // ======== role 3: gh1 = h1[t-1] @ Wh1 producer ========
    for (int t = 0; t < LSEQ; ++t) {
      poll64(f1g, lane, (unsigned)(t + 1));  // h1[t-1] ready (all blocks)
      const _Float16* Ap = h1buf + ((t + 1) & 1) * 16384 + (mhalf * 16 + l16) * 512 + 8 * lhi;
      f16x8 afr[16];
#pragma unroll
      for (int kc = 0; kc < 16; ++kc) afr[kc] = __builtin_bit_cast(f16x8, load16h<FAST>(Ap + kc * 32));
      asm volatile("s_waitcnt vmcnt(0)" ::: "memory");
      __builtin_amdgcn_sched_barrier(0);
      f32x4 a0 = {0,0,0,0}, a1 = {0,0,0,0}, a2 = {0,0,0,0};
#pragma unroll
      for (int kc = 0; kc < 16; ++kc) {
        a0 = __builtin_amdgcn_mfma_f32_16x16x32_f16(afr[kc], Wb2[(kc*3+0)*64+lane], a0, 0,0,0);
        a1 = __builtin_amdgcn_mfma_f32_16x16x32_f16(afr[kc], Wb2[(kc*3+1)*64+lane], a1, 0,0,0);
        a2 = __builtin_amdgcn_mfma_f32_16x16x32_f16(afr[kc], Wb2[(kc*3+2)*64+lane], a2, 0,0,0);
      }
      lds_poll(&sf[6 + mhalf], (unsigned)t);  // role2 consumed gh1[t-1]
#pragma unroll
      for (int q = 0; q < 4; ++q) {
        const int row = rowq0 + q;
        gh1buf[(0*32 + row)*16 + l16] = a0[q];
        gh1buf[(1*32 + row)*16 + l16] = a1[q];
        gh1buf[(2*32 + row)*16 + l16] = a2[q];
      }
      if (lane == 0) lds_post(&sf[4 + mhalf], (unsigned)(t + 1));
    }
  }
}

__global__ void __launch_bounds__(512, 2)
gru_kernel(const float* __restrict__ carry, const float* __restrict__ x,
           const float* __restrict__ bh0, const float* __restrict__ bh1,
           float* __restrict__ out, char* __restrict__ ws) {
  extern __shared__ char smem[];
  _Float16* Wlds = (_Float16*)smem;        // 147456 B: Wh0,Wi1,Wh1 fragment slices
  float* gi0buf = (float*)(smem + 147456); // 6144 B: [3 nt][32 row][16 col]
  float* gh1buf = (float*)(smem + 153600); // 6144 B
  __shared__ unsigned int sf[8];  // 0,1:gi0_rdy[mh] 2,3:gi0_cons 4,5:gh1_rdy 6,7:gh1_cons
  __shared__ int sh_g, sh_cid, sh_fast;

  const int tid = threadIdx.x;
  if (tid < 8) sf[tid] = 0u;

  // --- deadlock-proof group discovery (R4, verbatim): g = XCC, cid = rank ---
  if (tid == 0) {
    unsigned int xcc;
    asm volatile("s_getreg_b32 %0, hwreg(HW_REG_XCC_ID)" : "=s"(xcc));
    xcc &= 7u;
    unsigned int* rk = (unsigned int*)(ws + RANK_OFF) + xcc * 64;
    unsigned int* gb = (unsigned int*)(ws + GBAR_OFF);
    unsigned int* bd = (unsigned int*)(ws + BAD_OFF);
    unsigned int cid_raw = __hip_atomic_fetch_add(rk, 1u, __ATOMIC_RELAXED, __HIP_MEMORY_SCOPE_AGENT);
    asm volatile("s_waitcnt vmcnt(0)" ::: "memory");
    __hip_atomic_fetch_add(gb, 1u, __ATOMIC_RELAXED, __HIP_MEMORY_SCOPE_AGENT);
    while (__hip_atomic_load(gb, __ATOMIC_RELAXED, __HIP_MEMORY_SCOPE_AGENT) < 256u) {}
    unsigned int cnt = __hip_atomic_load(rk, __ATOMIC_RELAXED, __HIP_MEMORY_SCOPE_AGENT);
    if (cnt != 32u || cid_raw >= 32u)
      __hip_atomic_fetch_add(bd, 1u, __ATOMIC_RELAXED, __HIP_MEMORY_SCOPE_AGENT);
    asm volatile("s_waitcnt vmcnt(0)" ::: "memory");
    __hip_atomic_fetch_add(gb, 1u, __ATOMIC_RELAXED, __HIP_MEMORY_SCOPE_AGENT);
    while (__hip_atomic_load(gb, __ATOMIC_RELAXED, __HIP_MEMORY_SCOPE_AGENT) < 512u) {}
    unsigned int badv = __hip_atomic_load(bd, __ATOMIC_RELAXED, __HIP_MEMORY_SCOPE_AGENT);
    sh_fast = (badv == 0u);
    sh_g    = (badv == 0u) ? (int)xcc     : (int)(blockIdx.x & 7);
    sh_cid  = (badv == 0u) ? (int)cid_raw : (int)(blockIdx.x >> 3);
  }
  __syncthreads();
  const int g = sh_g, cid = sh_cid;

  // Stage recurrent-weight fragments into LDS.
  _Float16* wt = (_Float16*)(ws + WT_OFF);
  for (int w = 0; w < 3; ++w) {
    const f16x8* s8 = (const f16x8*)(wt + (size_t)(w * 32 + cid) * 24576);
    f16x8* d8 = (f16x8*)(Wlds + w * 24576);
    for (int i = tid; i < 3072; i += 512) d8[i] = s8[i];
  }
  __syncthreads();  // weights + sf ready; last block-wide sync

  if (sh_fast) run_scan<true >(g, cid, carry, x, bh0, bh1, out, ws, Wlds, gi0buf, gh1buf, sf);
  else         run_scan<false>(g, cid, carry, x, bh0, bh1, out, ws, Wlds, gi0buf, gh1buf, sf);
}

extern "C" void kernel_launch(void* const* d_in, const int* in_sizes, int n_in,
                              void* d_out, int out_size, void* d_ws, size_t ws_size,
                              hipStream_t stream) {
  const float* carry = (const float*)d_in[0];
  const float* x     = (const float*)d_in[1];
  const float* Wi0   = (const float*)d_in[2];
  const float* Wh0   = (const float*)d_in[3];
  const float* bh0   = (const float*)d_in[4];
  const float* Wi1   = (const float*)d_in[5];
  const float* Wh1   = (const float*)d_in[6];
  const float* bh1   = (const float*)d_in[7];
  float* out = (float*)d_out;
  char* ws = (char*)d_ws;

  prep_kernel<<<2048, 256, 0, stream>>>(Wh0, Wi1, Wh1, Wi0, ws);

  (void)hipFuncSetAttribute(reinterpret_cast<const void*>(gru_kernel),
                            hipFuncAttributeMaxDynamicSharedMemorySize, 159744);

  void* args[] = {(void*)&carry, (void*)&x, (void*)&bh0, (void*)&bh1, (void*)&out, (void*)&ws};
  (void)hipLaunchCooperativeKernel(reinterpret_cast<void*>(gru_kernel),
                                   dim3(256), dim3(512), args, 159744, stream);
}

// Round 9
// 8531.963 us; speedup vs baseline: 2.1053x; 2.0941x over previous
//
#include <hip/hip_runtime.h>

// 2-layer GRU scan: L=512, B=256, D=H=512, 3H=1536.
// Persistent cooperative kernel: 256 blocks (1/CU, LDS-pinned) x 512 threads.
// 8 groups x 32 blocks (g=bid&7); group owns 32 batch rows; layer0 step s and
// layer1 step s-1 run concurrently; ONE group barrier per super-step.
//
// R9 = R4's proven lockstep schedule + R6's proven flag primitive as barrier:
//  - arrive: block atomically stores phase k+1 to its OWN 128B slot (AGENT
//    scope, executes at IF$; no RMW, no convoy).
//  - wait: wave 0 polls the 32 slots in parallel (32 lanes, atomic loads +
//    ballot), then __syncthreads releases the block.
//  - h-state: sc0 sc1 stores/loads (IF$ coherence point; R2/R6-proven),
//    vmcnt(0) drained by __syncthreads before the flag post.
// NO non-IF$ signaling anywhere (R3/R5/R8 all hung on such paths). No
// discovery, no fallback, single code path.

#define LSEQ 512
#define TH3 1536

// ws layout (bytes)
#define WT_OFF   0                         // half WT[4][32][16][3][64][8] = 6291456
#define H0_OFF   6291456                   // half h0buf[8][2][32][512]    = 524288
#define H1_OFF   6815744                   // half h1buf[8][2][32][512]    = 524288
#define FBAR_OFF 7340032                   // flag[8][32][128B]            = 32768

typedef _Float16 f16x8 __attribute__((ext_vector_type(8)));
typedef float f32x4 __attribute__((ext_vector_type(4)));

__device__ __forceinline__ float sig_(float v) { return 1.0f / (1.0f + __expf(-v)); }
__device__ __forceinline__ float tanh_(float v) { return 2.0f / (1.0f + __expf(-2.0f * v)) - 1.0f; }

// h-state transport: IF$ coherence point (R2/R6-proven).
__device__ __forceinline__ f32x4 load16b(const void* p) {
  f32x4 r;
  asm volatile("global_load_dwordx4 %0, %1, off sc0 sc1" : "=v"(r) : "v"(p));
  return r;  // NOT ready until s_waitcnt vmcnt(0)
}
__device__ __forceinline__ void store2b(_Float16* p, _Float16 v) {
  asm volatile("global_store_short %0, %1, off sc0 sc1" :: "v"(p), "v"(v) : "memory");
}

// Flag barrier, ordinal k = 1,2,...  (R6-proven primitives only)
__device__ __forceinline__ void gbarrier(char* fb, unsigned int* myflag, int tid, int lane,
                                         unsigned int k) {
  __syncthreads();  // every wave's VMEM drained (compiler emits vmcnt(0) before s_barrier)
  if (tid < 64) {
    const unsigned int tgt = k + 1;
    if (tid == 0)
      __hip_atomic_store(myflag, tgt, __ATOMIC_RELAXED, __HIP_MEMORY_SCOPE_AGENT);
    unsigned int* p = (unsigned int*)(fb + (lane & 31) * 128);
    while (__ballot(__hip_atomic_load(p, __ATOMIC_RELAXED, __HIP_MEMORY_SCOPE_AGENT) >= tgt)
           != ~0ull)
      __builtin_amdgcn_s_sleep(1);
  }
  __syncthreads();
}

// Weight transpose fp32 -> fp16 MFMA B-fragment layout (unchanged).
// Fragment layout per (w, cid): [kc 0..15][nt 0..2][lane 0..63][e 0..7] halves,
// where gate col = nt*512 + cid*16 + (lane&15), k = kc*32 + 8*(lane>>4) + e.
__global__ void prep_kernel(const float* __restrict__ Wh0, const float* __restrict__ Wi1,
                            const float* __restrict__ Wh1, const float* __restrict__ Wi0,
                            char* __restrict__ ws) {
  const int b = blockIdx.x;          // 2048 blocks
  const int w = b >> 9;              // 0:Wh0 1:Wi1 2:Wh1 3:Wi0
  const int k = b & 511;
  const float* src = (w == 0) ? Wh0 : (w == 1) ? Wi1 : (w == 2) ? Wh1 : Wi0;
  _Float16* dst = (_Float16*)(ws + WT_OFF);
  const int kc = k >> 5;
  const int lthi = ((k >> 3) & 3) << 4;
  const int e = k & 7;
  for (int col = threadIdx.x; col < TH3; col += 256) {
    float v = src[(size_t)k * TH3 + col];
    int nt = col >> 9, c = col & 511, cid = c >> 4, j = c & 15;
    size_t idx = (size_t)(w * 32 + cid) * 24576 + (size_t)((kc * 3 + nt) * 64 + lthi + j) * 8 + e;
    dst[idx] = (_Float16)v;
  }
  if (b == 0) {  // zero barrier flags (every call, stream-ordered)
    unsigned int* z = (unsigned int*)(ws + FBAR_OFF);
    for (int i = threadIdx.x; i < 8192; i += 256) z[i] = 0u;
  }
}

__global__ void __launch_bounds__(512, 2)
gru_kernel(const float* __restrict__ carry, const float* __restrict__ x,
           const float* __restrict__ bh0, const float* __restrict__ bh1,
           float* __restrict__ out, char* __restrict__ ws) {
  extern __shared__ char smem[];
  _Float16* Wlds = (_Float16*)smem;     // 147456 B: Wh0,Wi1,Wh1 fragment slices
  float* GH = (float*)(smem + 147456);  // 12288 B: [2 layer][3 nt][32 row][16 col]

  const int tid = threadIdx.x;
  const int wid = tid >> 6, lane = tid & 63;
  const int l16 = lane & 15, lhi = lane >> 4;
  const int mhalf = wid & 1, role = wid >> 1;  // 0:gh0 1:gi0+ep0 2:gi1+ep1 3:gh1
  const int g = blockIdx.x & 7, cid = blockIdx.x >> 3;

  _Float16* wt = (_Float16*)(ws + WT_OFF);
  _Float16* h0buf = (_Float16*)(ws + H0_OFF) + (size_t)g * 32768;  // [2 parity][32 row][512]
  _Float16* h1buf = (_Float16*)(ws + H1_OFF) + (size_t)g * 32768;
  char* fb = ws + FBAR_OFF + (size_t)g * 32 * 128;
  unsigned int* myflag = (unsigned int*)(fb + cid * 128);
  unsigned int k = 0;

  // Stage this CU's recurrent-weight fragments into LDS.
  for (int w = 0; w < 3; ++w) {
    const f16x8* s8 = (const f16x8*)(wt + (size_t)(w * 32 + cid) * 24576);
    f16x8* d8 = (f16x8*)(Wlds + w * 24576);
    for (int i = tid; i < 3072; i += 512) d8[i] = s8[i];
  }

  const int hcol = cid * 16 + l16;
  const int rowq0 = mhalf * 16 + 4 * lhi;  // acc-tile rows rowq0+q (m89-verified C/D layout)

  float bR = 0.f, bZ = 0.f, bN = 0.f;
  f32x4 hst = {0.f, 0.f, 0.f, 0.f};  // fp32 recurrent state (roles 1,2)
  if (role == 1 || role == 2) {
    const float* bh = (role == 1) ? bh0 : bh1;
    bR = bh[hcol]; bZ = bh[512 + hcol]; bN = bh[1024 + hcol];
    const int loff = (role == 1) ? 0 : 512;
    _Float16* hb = (role == 1) ? h0buf : h1buf;
#pragma unroll
    for (int q = 0; q < 4; ++q) {
      float h = carry[(size_t)(g * 32 + rowq0 + q) * 1024 + loff + hcol];
      hst[q] = h;
      store2b(&hb[16384 + (rowq0 + q) * 512 + hcol], (_Float16)h);  // prefill parity-1
    }
    asm volatile("s_waitcnt vmcnt(0)" ::: "memory");
  }
  gbarrier(fb, myflag, tid, lane, ++k);

  const f16x8* Wb0 = (const f16x8*)Wlds;                 // Wh0 frags (LDS)
  const f16x8* Wb1 = (const f16x8*)(Wlds + 24576);       // Wi1 frags (LDS)
  const f16x8* Wb2 = (const f16x8*)(Wlds + 2 * 24576);   // Wh1 frags (LDS)
  const f16x8* WbX = (const f16x8*)(wt + (size_t)(3 * 32 + cid) * 24576);  // Wi0 frags (L2)

  for (int s = 0; s <= LSEQ; ++s) {
    const int pr = (s + 1) & 1;  // parity of state[s-1]
    const int pw = s & 1;        // parity of state[s] / state[s-2]
    f32x4 a0 = {0,0,0,0}, a1 = {0,0,0,0}, a2 = {0,0,0,0};

    if (role == 0 && s < LSEQ) {            // gh0 = h0[s-1] @ Wh0
      const _Float16* Ap = h0buf + pr * 16384 + (mhalf * 16 + l16) * 512 + 8 * lhi;
      f16x8 afr[16];
#pragma unroll
      for (int kc = 0; kc < 16; ++kc) afr[kc] = __builtin_bit_cast(f16x8, load16b(Ap + kc * 32));
      asm volatile("s_waitcnt vmcnt(0)" ::: "memory");
      __builtin_amdgcn_sched_barrier(0);
#pragma unroll
      for (int kc = 0; kc < 16; ++kc) {
        a0 = __builtin_amdgcn_mfma_f32_16x16x32_f16(afr[kc], Wb0[(kc*3+0)*64+lane], a0, 0,0,0);
        a1 = __builtin_amdgcn_mfma_f32_16x16x32_f16(afr[kc], Wb0[(kc*3+1)*64+lane], a1, 0,0,0);
        a2 = __builtin_amdgcn_mfma_f32_16x16x32_f16(afr[kc], Wb0[(kc*3+2)*64+lane], a2, 0,0,0);
      }
#pragma unroll
      for (int q = 0; q < 4; ++q) {
        GH[(0*32 + rowq0 + q)*16 + l16] = a0[q];
        GH[(1*32 + rowq0 + q)*16 + l16] = a1[q];
        GH[(2*32 + rowq0 + q)*16 + l16] = a2[q];
      }
    } else if (role == 3 && s >= 1) {       // gh1 = h1[s-2] @ Wh1
      const _Float16* Ap = h1buf + pw * 16384 + (mhalf * 16 + l16) * 512 + 8 * lhi;
      f16x8 afr[16];
#pragma unroll
      for (int kc = 0; kc < 16; ++kc) afr[kc] = __builtin_bit_cast(f16x8, load16b(Ap + kc * 32));
      asm volatile("s_waitcnt vmcnt(0)" ::: "memory");
      __builtin_amdgcn_sched_barrier(0);
#pragma unroll
      for (int kc = 0; kc < 16; ++kc) {
        a0 = __builtin_amdgcn_mfma_f32_16x16x32_f16(afr[kc], Wb2[(kc*3+0)*64+lane], a0, 0,0,0);
        a1 = __builtin_amdgcn_mfma_f32_16x16x32_f16(afr[kc], Wb2[(kc*3+1)*64+lane], a1, 0,0,0);
        a2 = __builtin_amdgcn_mfma_f32_16x16x32_f16(afr[kc], Wb2[(kc*3+2)*64+lane], a2, 0,0,0);
      }
#pragma unroll
      for (int q = 0; q < 4; ++q) {
        GH[((3+0)*32 + rowq0 + q)*16 + l16] = a0[q];
        GH[((3+1)*32 + rowq0 + q)*16 + l16] = a1[q];
        GH[((3+2)*32 + rowq0 + q)*16 + l16] = a2[q];
      }
    } else if (role == 1 && s < LSEQ) {     // gi0 = x[s] @ Wi0
      const float* xp = x + ((size_t)s * 256 + g * 32 + mhalf * 16 + l16) * 512 + 8 * lhi;
#pragma unroll
      for (int kc = 0; kc < 16; ++kc) {
        f32x4 xa = *(const f32x4*)(xp + kc * 32);
        f32x4 xb = *(const f32x4*)(xp + kc * 32 + 4);
        f16x8 a;
        a[0]=(_Float16)xa[0]; a[1]=(_Float16)xa[1]; a[2]=(_Float16)xa[2]; a[3]=(_Float16)xa[3];
        a[4]=(_Float16)xb[0]; a[5]=(_Float16)xb[1]; a[6]=(_Float16)xb[2]; a[7]=(_Float16)xb[3];
        a0 = __builtin_amdgcn_mfma_f32_16x16x32_f16(a, WbX[(kc*3+0)*64+lane], a0, 0,0,0);
        a1 = __builtin_amdgcn_mfma_f32_16x16x32_f16(a, WbX[(kc*3+1)*64+lane], a1, 0,0,0);
        a2 = __builtin_amdgcn_mfma_f32_16x16x32_f16(a, WbX[(kc*3+2)*64+lane], a2, 0,0,0);
      }
    } else if (role == 2 && s >= 1) {       // gi1 = h0[s-1] @ Wi1
      const _Float16* Ap = h0buf + pr * 16384 + (mhalf * 16 + l16) * 512 + 8 * lhi;
      f16x8 afr[16];
#pragma unroll
      for (int kc = 0; kc < 16; ++kc) afr[kc] = __builtin_bit_cast(f16x8, load16b(Ap + kc * 32));
      asm volatile("s_waitcnt vmcnt(0)" ::: "memory");
      __builtin_amdgcn_sched_barrier(0);
#pragma unroll
      for (int kc = 0; kc < 16; ++kc) {
        a0 = __builtin_amdgcn_mfma_f32_16x16x32_f16(afr[kc], Wb1[(kc*3+0)*64+lane], a0, 0,0,0);
        a1 = __builtin_amdgcn_mfma_f32_16x16x32_f16(afr[kc], Wb1[(kc*3+1)*64+lane], a1, 0,0,0);
        a2 = __builtin_amdgcn_mfma_f32_16x16x32_f16(afr[kc], Wb1[(kc*3+2)*64+lane], a2, 0,0,0);
      }
    }
    __syncthreads();  // gh accs visible in LDS

    if (role == 1 && s < LSEQ) {            // layer-0 epilogue -> h0[s]
#pragma unroll
      for (int q = 0; q < 4; ++q) {
        const int row = rowq0 + q;
        float r = sig_(a0[q] + GH[(0*32 + row)*16 + l16] + bR);
        float z = sig_(a1[q] + GH[(1*32 + row)*16 + l16] + bZ);
        float n = tanh_(a2[q] + r * (GH[(2*32 + row)*16 + l16] + bN));
        float h = (1.0f - z) * n + z * hst[q];
        hst[q] = h;
        store2b(&h0buf[pw * 16384 + row * 512 + hcol], (_Float16)h);
        if (s == LSEQ - 1) out[(size_t)(g * 32 + row) * 1024 + hcol] = h;  // carry h0
      }
      asm volatile("s_waitcnt vmcnt(0)" ::: "memory");
    } else if (role == 2 && s >= 1) {       // layer-1 epilogue -> h1[s-1]
#pragma unroll
      for (int q = 0; q < 4; ++q) {
        const int row = rowq0 + q;
        float r = sig_(a0[q] + GH[((3+0)*32 + row)*16 + l16] + bR);
        float z = sig_(a1[q] + GH[((3+1)*32 + row)*16 + l16] + bZ);
        float n = tanh_(a2[q] + r * (GH[((3+2)*32 + row)*16 + l16] + bN));
        float h = (1.0f - z) * n + z * hst[q];
        hst[q] = h;
        store2b(&h1buf[pr * 16384 + row * 512 + hcol], (_Float16)h);
        out[(size_t)262144 + ((size_t)(s - 1) * 256 + g * 32 + row) * 512 + hcol] = h;  // y[s-1]
        if (s == LSEQ) out[(size_t)(g * 32 + row) * 1024 + 512 + hcol] = h;             // carry h1
      }
      asm volatile("s_waitcnt vmcnt(0)" ::: "memory");
    }
    gbarrier(fb, myflag, tid, lane, ++k);
  }
}

extern "C" void kernel_launch(void* const* d_in, const int* in_sizes, int n_in,
                              void* d_out, int out_size, void* d_ws, size_t ws_size,
                              hipStream_t stream) {
  const float* carry = (const float*)d_in[0];
  const float* x     = (const float*)d_in[1];
  const float* Wi0   = (const float*)d_in[2];
  const float* Wh0   = (const float*)d_in[3];
  const float* bh0   = (const float*)d_in[4];
  const float* Wi1   = (const float*)d_in[5];
  const float* Wh1   = (const float*)d_in[6];
  const float* bh1   = (const float*)d_in[7];
  float* out = (float*)d_out;
  char* ws = (char*)d_ws;

  prep_kernel<<<2048, 256, 0, stream>>>(Wh0, Wi1, Wh1, Wi0, ws);

  (void)hipFuncSetAttribute(reinterpret_cast<const void*>(gru_kernel),
                            hipFuncAttributeMaxDynamicSharedMemorySize, 159744);

  void* args[] = {(void*)&carry, (void*)&x, (void*)&bh0, (void*)&bh1, (void*)&out, (void*)&ws};
  (void)hipLaunchCooperativeKernel(reinterpret_cast<void*>(gru_kernel),
                                   dim3(256), dim3(512), args, 159744, stream);
}